// Round 4
// baseline (358.179 us; speedup 1.0000x reference)
//
#include <hip/hip_runtime.h>

// Problem constants (fixed by the reference setup_inputs)
#define T_ 4096
#define D_ 4096
#define O_ 4096
#define L_ 32
#define R_ 8

constexpr int BM = 256, BN = 256, BK = 64;
constexpr int KEXT = L_ * R_;            // 256 extension columns (4 K-tiles)
constexpr int NT = D_ / BK + KEXT / BK;  // 64 + 4 = 68 K-tiles (even)

typedef __bf16 bf16x8 __attribute__((ext_vector_type(8)));
typedef unsigned short u16x8 __attribute__((ext_vector_type(8)));
typedef float f32x4 __attribute__((ext_vector_type(4)));

// fp32 -> bf16 round-to-nearest-even
__device__ __forceinline__ unsigned short f2bf(float f) {
    unsigned int u = __float_as_uint(f);
    u = (u + 0x7fffu + ((u >> 16) & 1u)) >> 16;
    return (unsigned short)u;
}

__device__ __forceinline__ float bf2f(unsigned short u) {
    return __uint_as_float(((unsigned int)u) << 16);
}

// async global->LDS, 16B per lane. LDS dest = wave-uniform base + lane*16.
__device__ __forceinline__ void load_lds16(const void* g, void* l) {
    __builtin_amdgcn_global_load_lds((__attribute__((address_space(1))) void*)g,
                                     (__attribute__((address_space(3))) void*)l,
                                     16, 0, 0);
}

// compiler-only memory fence (no instruction) + raw barrier (no vmcnt drain)
#define MEMF() asm volatile("" ::: "memory")
#define BARRIER() do { MEMF(); __builtin_amdgcn_s_barrier(); MEMF(); } while (0)

// ---------------------------------------------------------------------------
// Kernel 1 (flat prep, all sections streaming/BW-bound), by blockIdx.x:
//   [0, 16384)     : W fp32->bf16  -> wbuf       (O*D)
//   [16384, 32768) : x fp32->bf16  -> xbuf       (T*D)
//   [32768, 33792) : lora_a fp32->bf16 -> abuf   (L*R*D)
//   [33792, 34816) : Bext[o][l*8+r] = bf16(lora_b[l,0,o,r])
//   [34816, 35328) : Aext zero-fill (T*KEXT bf16)
// ---------------------------------------------------------------------------
__global__ __launch_bounds__(256) void prep(const float* __restrict__ w,
                                            unsigned short* __restrict__ wbuf,
                                            const float* __restrict__ x,
                                            unsigned short* __restrict__ xbuf,
                                            const float* __restrict__ lora_a,
                                            unsigned short* __restrict__ abuf,
                                            const float* __restrict__ lora_b,
                                            unsigned short* __restrict__ bext,
                                            unsigned short* __restrict__ aext) {
    const int b = blockIdx.x;
    const int tid = threadIdx.x;
    if (b < 16384) {
        const int i = (b * 256 + tid) * 4;
        float4 v = *(const float4*)&w[i];
        ushort4 o;
        o.x = f2bf(v.x); o.y = f2bf(v.y); o.z = f2bf(v.z); o.w = f2bf(v.w);
        *(ushort4*)&wbuf[i] = o;
        return;
    }
    if (b < 32768) {
        const int i = ((b - 16384) * 256 + tid) * 4;
        float4 v = *(const float4*)&x[i];
        ushort4 o;
        o.x = f2bf(v.x); o.y = f2bf(v.y); o.z = f2bf(v.z); o.w = f2bf(v.w);
        *(ushort4*)&xbuf[i] = o;
        return;
    }
    if (b < 33792) {
        const int i = ((b - 32768) * 256 + tid) * 4;
        float4 v = *(const float4*)&lora_a[i];
        ushort4 o;
        o.x = f2bf(v.x); o.y = f2bf(v.y); o.z = f2bf(v.z); o.w = f2bf(v.w);
        *(ushort4*)&abuf[i] = o;
        return;
    }
    if (b < 34816) {
        // Bext: 4 output rows per block, one 64-lane wave per row.
        const int o = (b - 33792) * 4 + (tid >> 6);
        const int lane = tid & 63;
        const int l = lane >> 1;                 // lora id 0..31
        const int r0 = (lane & 1) * 4;           // r offset 0 or 4
        float4 v = *(const float4*)&lora_b[((size_t)l * O_ + o) * R_ + r0];
        ushort4 ov;
        ov.x = f2bf(v.x); ov.y = f2bf(v.y); ov.z = f2bf(v.z); ov.w = f2bf(v.w);
        *(ushort4*)&bext[(size_t)o * KEXT + lane * 4] = ov;
        return;
    }
    // Aext zero-fill: 16B per thread
    {
        const int i = ((b - 34816) * 256 + tid) * 8;
        uint4 z = {0u, 0u, 0u, 0u};
        *(uint4*)&aext[i] = z;
    }
}

// ---------------------------------------------------------------------------
// Kernel 2: grouped LoRA shrink. Grid = 32 loras x 16 token-slices.
// Block (l, slice): stages A_l (8x4096 bf16 = 64 KB) in LDS once, preloads
// its 256 tli values, then for each token with tli==l computes the 8 dots
// from LDS and writes Aext[t][l*8+r] = bf16(dot). A-traffic: 32 MB from L2
// (same-l blocks land on the same XCD since block id = l mod 32 => id%8 = l%8).
// Replaces the 500 MB per-token A-gather of previous rounds.
// ---------------------------------------------------------------------------
__global__ __launch_bounds__(256) void shrink_grouped(const unsigned short* __restrict__ abuf,
                                                      const unsigned short* __restrict__ xbuf,
                                                      const int* __restrict__ tli,
                                                      unsigned short* __restrict__ aext) {
    __shared__ unsigned short Al[R_ * D_];   // 64 KB
    __shared__ int tl[256];
    __shared__ float red[4][R_];

    const int tid = threadIdx.x;
    const int lane = tid & 63;
    const int wave = tid >> 6;
    const int l = blockIdx.x & 31;
    const int slice = blockIdx.x >> 5;

    // stage A_l: 64 KB = 64 wave-issues of 64 lanes x 16 B, linear layout
    const unsigned short* as = abuf + (size_t)l * R_ * D_;
#pragma unroll
    for (int j = 0; j < 16; ++j) {
        const int c = j * 4 + wave;          // 0..63 chunk of 1024 B
        load_lds16(as + c * 512 + lane * 8, &Al[c * 512]);
    }
    tl[tid] = tli[slice * 256 + tid];
    __syncthreads();   // drains vmcnt -> Al and tl visible

    for (int i = 0; i < 256; ++i) {
        if (tl[i] != l) continue;            // uniform branch
        const int t = slice * 256 + i;
        const unsigned short* xr = xbuf + (size_t)t * D_;
        // thread covers d = tid*8..+7 and d = 2048 + tid*8..+7
        u16x8 xv0 = *(const u16x8*)&xr[tid * 8];
        u16x8 xv1 = *(const u16x8*)&xr[2048 + tid * 8];
        float acc[R_];
#pragma unroll
        for (int r = 0; r < R_; ++r) {
            u16x8 a0 = *(const u16x8*)&Al[r * D_ + tid * 8];
            u16x8 a1 = *(const u16x8*)&Al[r * D_ + 2048 + tid * 8];
            float s = 0.f;
#pragma unroll
            for (int e = 0; e < 8; ++e) {
                s += bf2f(xv0[e]) * bf2f(a0[e]);
                s += bf2f(xv1[e]) * bf2f(a1[e]);
            }
            acc[r] = s;
        }
#pragma unroll
        for (int r = 0; r < R_; ++r) {
#pragma unroll
            for (int off = 32; off > 0; off >>= 1)
                acc[r] += __shfl_xor(acc[r], off, 64);
        }
        if (lane < R_) red[wave][lane] = acc[lane];
        __syncthreads();
        if (tid < R_) {
            float s = red[0][tid] + red[1][tid] + red[2][tid] + red[3][tid];
            aext[(size_t)t * KEXT + l * R_ + tid] = f2bf(s);
        }
        __syncthreads();
    }
}

// ---------------------------------------------------------------------------
// Kernel 3: 256x256 bf16 MFMA GEMM over K = 4096 + 256 (LoRA expand folded in
// as 4 extra K-tiles read from aext/bext). Proven round-3 skeleton, unchanged:
// per K-tile 4 phases of {ds_reads; barrier; setprio MFMA x16 setprio; barrier},
// staging for tile t+2 spread at phase starts, vmcnt(8) once per tile.
// Epilogue: out = acc + base_bias + (valid ? bias_st : 0).
// ---------------------------------------------------------------------------
__global__ __launch_bounds__(512, 2) void gemm_lora(const short* __restrict__ xb,
                                                    const short* __restrict__ wb,
                                                    const short* __restrict__ aext,
                                                    const short* __restrict__ bext,
                                                    const float* __restrict__ base_bias,
                                                    const float* __restrict__ bias_st,
                                                    const int* __restrict__ tli,
                                                    float* __restrict__ out) {
    extern __shared__ short smem[];
    short* As0 = smem;                 // 256*64 shorts = 32 KB
    short* Bs0 = smem + 16384;
    short* As1 = smem + 32768;
    short* Bs1 = smem + 49152;

    const int tid = threadIdx.x;
    const int lane = tid & 63;
    const int wid = tid >> 6;          // 0..7
    const int wm = wid >> 2;           // 0..1
    const int wn = wid & 3;            // 0..3
    const int l15 = lane & 15;
    const int quad = lane >> 4;
    const int swz = l15 & 7;

    // bijective XCD swizzle over 256 blocks (16x16 tile grid, nwg%8==0)
    const int nid = (blockIdx.x & 7) * 32 + (blockIdx.x >> 3);
    const int t0 = (nid >> 4) * BM;
    const int o0 = (nid & 15) * BN;

    // staging source per-lane: row-within-8 = lane>>3, pre-swizzled chunk
    const int lr = lane >> 3;
    const int lc = (lane & 7) ^ lr;
    const short* agD = xb   + (size_t)(t0 + wid * 8 + lr) * D_   + lc * 8;
    const short* bgD = wb   + (size_t)(o0 + wid * 8 + lr) * D_   + lc * 8;
    const short* agE = aext + (size_t)(t0 + wid * 8 + lr) * KEXT + lc * 8;
    const short* bgE = bext + (size_t)(o0 + wid * 8 + lr) * KEXT + lc * 8;

    // region i covers tile rows [i*64, i*64+64); wave writes its 8 rows.
    // kt < 64 reads the main matrices; kt >= 64 reads the extension buffers.
    auto stA = [&](short* A_, int i, int kt) {
        const short* src = (kt < 64)
            ? agD + (size_t)i * 64 * D_   + (size_t)kt * 64
            : agE + (size_t)i * 64 * KEXT + (size_t)(kt - 64) * 64;
        load_lds16(src, A_ + (i * 64 + wid * 8) * 64);
    };
    auto stB = [&](short* B_, int i, int kt) {
        const short* src = (kt < 64)
            ? bgD + (size_t)i * 64 * D_   + (size_t)kt * 64
            : bgE + (size_t)i * 64 * KEXT + (size_t)(kt - 64) * 64;
        load_lds16(src, B_ + (i * 64 + wid * 8) * 64);
    };

    f32x4 acc[8][4];
#pragma unroll
    for (int mi = 0; mi < 8; ++mi)
#pragma unroll
        for (int ni = 0; ni < 4; ++ni) acc[mi][ni] = f32x4{0.f, 0.f, 0.f, 0.f};

    bf16x8 af[4][2];    // current qm-half A frags (reused for HI half)
    bf16x8 bfr[4][2];   // all B frags, live across the whole K-tile

    const int arow0 = wm * 128 + l15;
    const int brow0 = wn * 64 + l15;

    auto rdA = [&](const short* A_, int mi, int kk) {
        return *(const bf16x8*)&A_[(arow0 + mi * 16) * 64 + (((kk << 2) + quad) ^ swz) * 8];
    };
    auto rdB = [&](const short* B_, int ni, int kk) {
        return *(const bf16x8*)&B_[(brow0 + ni * 16) * 64 + (((kk << 2) + quad) ^ swz) * 8];
    };

    // prologue: tile 0 -> buf0, tile 1 -> buf1. Group order [A0,A2,B0..B3,A1,A3]
    stA(As0, 0, 0); stA(As0, 2, 0); stB(Bs0, 0, 0); stB(Bs0, 1, 0);
    stB(Bs0, 2, 0); stB(Bs0, 3, 0); stA(As0, 1, 0); stA(As0, 3, 0);
    stA(As1, 0, 1); stA(As1, 2, 1); stB(Bs1, 0, 1); stB(Bs1, 1, 1);
    stB(Bs1, 2, 1); stB(Bs1, 3, 1); stA(As1, 1, 1); stA(As1, 3, 1);
    asm volatile("s_waitcnt vmcnt(8)" ::: "memory");   // tile 0 landed, tile 1 in flight
    BARRIER();

    auto do_tile = [&](int t, short* A_, short* B_) {
        const bool st = (t + 2 < NT);
        const int k2 = t + 2;

        // ---- phase 0: read A[mi0-3]+B[ni0-1]; MFMA mi0-3 x ni0-1
#pragma unroll
        for (int mi = 0; mi < 4; ++mi)
#pragma unroll
            for (int kk = 0; kk < 2; ++kk) af[mi][kk] = rdA(A_, mi, kk);
#pragma unroll
        for (int ni = 0; ni < 2; ++ni)
#pragma unroll
            for (int kk = 0; kk < 2; ++kk) bfr[ni][kk] = rdB(B_, ni, kk);
        BARRIER();
        __builtin_amdgcn_s_setprio(1);
#pragma unroll
        for (int kk = 0; kk < 2; ++kk)
#pragma unroll
            for (int mi = 0; mi < 4; ++mi)
#pragma unroll
                for (int ni = 0; ni < 2; ++ni)
                    acc[mi][ni] = __builtin_amdgcn_mfma_f32_16x16x32_bf16(
                        af[mi][kk], bfr[ni][kk], acc[mi][ni], 0, 0, 0);
        __builtin_amdgcn_s_setprio(0);
        BARRIER();   // A regions 0,2 of this buf fully consumed

        // ---- phase 1: stage t+2 A0,A2; read B[ni2-3]; MFMA mi0-3 x ni2-3
        if (st) { stA(A_, 0, k2); stA(A_, 2, k2); }
#pragma unroll
        for (int ni = 2; ni < 4; ++ni)
#pragma unroll
            for (int kk = 0; kk < 2; ++kk) bfr[ni][kk] = rdB(B_, ni, kk);
        BARRIER();
        __builtin_amdgcn_s_setprio(1);
#pragma unroll
        for (int kk = 0; kk < 2; ++kk)
#pragma unroll
            for (int mi = 0; mi < 4; ++mi)
#pragma unroll
                for (int ni = 2; ni < 4; ++ni)
                    acc[mi][ni] = __builtin_amdgcn_mfma_f32_16x16x32_bf16(
                        af[mi][kk], bfr[ni][kk], acc[mi][ni], 0, 0, 0);
        __builtin_amdgcn_s_setprio(0);
        BARRIER();   // all B regions of this buf fully consumed

        // ---- phase 2: stage t+2 B0-B3; read A[mi4-7]; MFMA mi4-7 x ni0-1
        if (st) { stB(B_, 0, k2); stB(B_, 1, k2); stB(B_, 2, k2); stB(B_, 3, k2); }
#pragma unroll
        for (int mi = 0; mi < 4; ++mi)
#pragma unroll
            for (int kk = 0; kk < 2; ++kk) af[mi][kk] = rdA(A_, mi + 4, kk);
        BARRIER();
        __builtin_amdgcn_s_setprio(1);
#pragma unroll
        for (int kk = 0; kk < 2; ++kk)
#pragma unroll
            for (int mi = 0; mi < 4; ++mi)
#pragma unroll
                for (int ni = 0; ni < 2; ++ni)
                    acc[mi + 4][ni] = __builtin_amdgcn_mfma_f32_16x16x32_bf16(
                        af[mi][kk], bfr[ni][kk], acc[mi + 4][ni], 0, 0, 0);
        __builtin_amdgcn_s_setprio(0);
        BARRIER();   // A regions 1,3 of this buf fully consumed

        // ---- phase 3: stage t+2 A1,A3; MFMA mi4-7 x ni2-3; tile-end wait
        if (st) { stA(A_, 1, k2); stA(A_, 3, k2); }
        BARRIER();
        __builtin_amdgcn_s_setprio(1);
#pragma unroll
        for (int kk = 0; kk < 2; ++kk)
#pragma unroll
            for (int mi = 0; mi < 4; ++mi)
#pragma unroll
                for (int ni = 2; ni < 4; ++ni)
                    acc[mi + 4][ni] = __builtin_amdgcn_mfma_f32_16x16x32_bf16(
                        af[mi][kk], bfr[ni][kk], acc[mi + 4][ni], 0, 0, 0);
        __builtin_amdgcn_s_setprio(0);
        // youngest 8 outstanding = tile t+2's group -> tiles t+1 (and older) landed
        if (st) { asm volatile("s_waitcnt vmcnt(8)" ::: "memory"); }
        else    { asm volatile("s_waitcnt vmcnt(0)" ::: "memory"); }
        BARRIER();
    };

    for (int tt = 0; tt < NT; tt += 2) {
        do_tile(tt, As0, Bs0);
        do_tile(tt + 1, As1, Bs1);
    }

    // Epilogue: C/D layout col = lane&15, row = quad*4 + reg (verified mapping)
    const int col_base = o0 + wn * 64 + l15;
    float bb[4];
#pragma unroll
    for (int ni = 0; ni < 4; ++ni) bb[ni] = base_bias[col_base + ni * 16];
#pragma unroll
    for (int mi = 0; mi < 8; ++mi) {
#pragma unroll
        for (int reg = 0; reg < 4; ++reg) {
            const int row = t0 + wm * 128 + mi * 16 + quad * 4 + reg;
            const int idx = tli[row];
            const bool valid = (idx >= 0);
#pragma unroll
            for (int ni = 0; ni < 4; ++ni) {
                const int col = col_base + ni * 16;
                float r = acc[mi][ni][reg] + bb[ni];
                if (valid) r += bias_st[(size_t)idx * O_ + col];
                out[(size_t)row * O_ + col] = r;
            }
        }
    }
}

// ---------------------------------------------------------------------------
extern "C" void kernel_launch(void* const* d_in, const int* in_sizes, int n_in,
                              void* d_out, int out_size, void* d_ws, size_t ws_size,
                              hipStream_t stream) {
    const float* x    = (const float*)d_in[0];   // [T,D]
    const float* w    = (const float*)d_in[1];   // [O,D]
    const float* bb   = (const float*)d_in[2];   // [O]
    const float* la   = (const float*)d_in[3];   // [L,1,R,D]
    const float* lb   = (const float*)d_in[4];   // [L,1,O,R]
    const float* bs   = (const float*)d_in[5];   // [L,1,O]
    const int*   tli  = (const int*)d_in[6];     // [T]
    float* out = (float*)d_out;

    static bool inited = false;
    if (!inited) {
        (void)hipFuncSetAttribute((const void*)gemm_lora,
                                  hipFuncAttributeMaxDynamicSharedMemorySize, 131072);
        inited = true;
    }

    // workspace: xb | wb | aext | bext | abuf  (all bf16)
    unsigned short* xb   = (unsigned short*)d_ws;
    unsigned short* wb   = xb + (size_t)T_ * D_;
    unsigned short* aext = wb + (size_t)O_ * D_;
    unsigned short* bext = aext + (size_t)T_ * KEXT;
    unsigned short* abuf = bext + (size_t)O_ * KEXT;

    prep<<<35328, 256, 0, stream>>>(w, wb, x, xb, la, abuf, lb, bext, aext);
    shrink_grouped<<<512, 256, 0, stream>>>(abuf, xb, tli, aext);
    gemm_lora<<<(T_ / BM) * (O_ / BN), 512, 131072, stream>>>(
        (const short*)xb, (const short*)wb, (const short*)aext, (const short*)bext,
        bb, bs, tli, out);
}

// Round 5
// 356.203 us; speedup vs baseline: 1.0055x; 1.0055x over previous
//
#include <hip/hip_runtime.h>

// Problem constants (fixed by the reference setup_inputs)
#define T_ 4096
#define D_ 4096
#define O_ 4096
#define L_ 32
#define R_ 8

constexpr int BM = 256, BN = 256, BK = 64;
constexpr int KEXT = L_ * R_;            // 256 extension columns (4 K-tiles)
constexpr int NT = D_ / BK + KEXT / BK;  // 64 + 4 = 68 K-tiles (even)

typedef __bf16 bf16x8 __attribute__((ext_vector_type(8)));
typedef unsigned short u16x8 __attribute__((ext_vector_type(8)));
typedef float f32x4 __attribute__((ext_vector_type(4)));

// fp32 -> bf16 round-to-nearest-even
__device__ __forceinline__ unsigned short f2bf(float f) {
    unsigned int u = __float_as_uint(f);
    u = (u + 0x7fffu + ((u >> 16) & 1u)) >> 16;
    return (unsigned short)u;
}

__device__ __forceinline__ float bf2f(unsigned short u) {
    return __uint_as_float(((unsigned int)u) << 16);
}

// async global->LDS, 16B per lane. LDS dest = wave-uniform base + lane*16.
__device__ __forceinline__ void load_lds16(const void* g, void* l) {
    __builtin_amdgcn_global_load_lds((__attribute__((address_space(1))) void*)g,
                                     (__attribute__((address_space(3))) void*)l,
                                     16, 0, 0);
}

// compiler-only memory fence (no instruction) + raw barrier (no vmcnt drain)
#define MEMF() asm volatile("" ::: "memory")
#define BARRIER() do { MEMF(); __builtin_amdgcn_s_barrier(); MEMF(); } while (0)

// ---------------------------------------------------------------------------
// Kernel 1 (flat prep, all sections streaming/BW-bound), by blockIdx.x:
//   [0, 16384)     : W fp32->bf16  -> wbuf       (O*D)
//   [16384, 32768) : x fp32->bf16  -> xbuf       (T*D)
//   [32768, 33792) : lora_a fp32->bf16 -> abuf   (L*R*D)
//   [33792, 34816) : Bext[o][l*8+r] = bf16(lora_b[l,0,o,r])
//   [34816, 35328) : Aext zero-fill (T*KEXT bf16)
// ---------------------------------------------------------------------------
__global__ __launch_bounds__(256) void prep(const float* __restrict__ w,
                                            unsigned short* __restrict__ wbuf,
                                            const float* __restrict__ x,
                                            unsigned short* __restrict__ xbuf,
                                            const float* __restrict__ lora_a,
                                            unsigned short* __restrict__ abuf,
                                            const float* __restrict__ lora_b,
                                            unsigned short* __restrict__ bext,
                                            unsigned short* __restrict__ aext) {
    const int b = blockIdx.x;
    const int tid = threadIdx.x;
    if (b < 16384) {
        const int i = (b * 256 + tid) * 4;
        float4 v = *(const float4*)&w[i];
        ushort4 o;
        o.x = f2bf(v.x); o.y = f2bf(v.y); o.z = f2bf(v.z); o.w = f2bf(v.w);
        *(ushort4*)&wbuf[i] = o;
        return;
    }
    if (b < 32768) {
        const int i = ((b - 16384) * 256 + tid) * 4;
        float4 v = *(const float4*)&x[i];
        ushort4 o;
        o.x = f2bf(v.x); o.y = f2bf(v.y); o.z = f2bf(v.z); o.w = f2bf(v.w);
        *(ushort4*)&xbuf[i] = o;
        return;
    }
    if (b < 33792) {
        const int i = ((b - 32768) * 256 + tid) * 4;
        float4 v = *(const float4*)&lora_a[i];
        ushort4 o;
        o.x = f2bf(v.x); o.y = f2bf(v.y); o.z = f2bf(v.z); o.w = f2bf(v.w);
        *(ushort4*)&abuf[i] = o;
        return;
    }
    if (b < 34816) {
        // Bext: 4 output rows per block, one 64-lane wave per row.
        const int o = (b - 33792) * 4 + (tid >> 6);
        const int lane = tid & 63;
        const int l = lane >> 1;                 // lora id 0..31
        const int r0 = (lane & 1) * 4;           // r offset 0 or 4
        float4 v = *(const float4*)&lora_b[((size_t)l * O_ + o) * R_ + r0];
        ushort4 ov;
        ov.x = f2bf(v.x); ov.y = f2bf(v.y); ov.z = f2bf(v.z); ov.w = f2bf(v.w);
        *(ushort4*)&bext[(size_t)o * KEXT + lane * 4] = ov;
        return;
    }
    // Aext zero-fill: 16B per thread
    {
        const int i = ((b - 34816) * 256 + tid) * 8;
        uint4 z = {0u, 0u, 0u, 0u};
        *(uint4*)&aext[i] = z;
    }
}

// ---------------------------------------------------------------------------
// Kernel 2: grouped LoRA shrink. Grid = 32 loras x 16 token-slices.
// Block (l, slice): stages A_l (8x4096 bf16 = 64 KB) in LDS once, preloads
// its 256 tli values, then for each token with tli==l computes the 8 dots
// from LDS and writes Aext[t][l*8+r] = bf16(dot).
// ---------------------------------------------------------------------------
__global__ __launch_bounds__(256) void shrink_grouped(const unsigned short* __restrict__ abuf,
                                                      const unsigned short* __restrict__ xbuf,
                                                      const int* __restrict__ tli,
                                                      unsigned short* __restrict__ aext) {
    __shared__ unsigned short Al[R_ * D_];   // 64 KB
    __shared__ int tl[256];
    __shared__ float red[4][R_];

    const int tid = threadIdx.x;
    const int lane = tid & 63;
    const int wave = tid >> 6;
    const int l = blockIdx.x & 31;
    const int slice = blockIdx.x >> 5;

    // stage A_l: 64 KB = 64 wave-issues of 64 lanes x 16 B, linear layout
    const unsigned short* as = abuf + (size_t)l * R_ * D_;
#pragma unroll
    for (int j = 0; j < 16; ++j) {
        const int c = j * 4 + wave;          // 0..63 chunk of 1024 B
        load_lds16(as + c * 512 + lane * 8, &Al[c * 512]);
    }
    tl[tid] = tli[slice * 256 + tid];
    __syncthreads();   // drains vmcnt -> Al and tl visible

    for (int i = 0; i < 256; ++i) {
        if (tl[i] != l) continue;            // uniform branch
        const int t = slice * 256 + i;
        const unsigned short* xr = xbuf + (size_t)t * D_;
        // thread covers d = tid*8..+7 and d = 2048 + tid*8..+7
        u16x8 xv0 = *(const u16x8*)&xr[tid * 8];
        u16x8 xv1 = *(const u16x8*)&xr[2048 + tid * 8];
        float acc[R_];
#pragma unroll
        for (int r = 0; r < R_; ++r) {
            u16x8 a0 = *(const u16x8*)&Al[r * D_ + tid * 8];
            u16x8 a1 = *(const u16x8*)&Al[r * D_ + 2048 + tid * 8];
            float s = 0.f;
#pragma unroll
            for (int e = 0; e < 8; ++e) {
                s += bf2f(xv0[e]) * bf2f(a0[e]);
                s += bf2f(xv1[e]) * bf2f(a1[e]);
            }
            acc[r] = s;
        }
#pragma unroll
        for (int r = 0; r < R_; ++r) {
#pragma unroll
            for (int off = 32; off > 0; off >>= 1)
                acc[r] += __shfl_xor(acc[r], off, 64);
        }
        if (lane < R_) red[wave][lane] = acc[lane];
        __syncthreads();
        if (tid < R_) {
            float s = red[0][tid] + red[1][tid] + red[2][tid] + red[3][tid];
            aext[(size_t)t * KEXT + l * R_ + tid] = f2bf(s);
        }
        __syncthreads();
    }
}

// ---------------------------------------------------------------------------
// Kernel 3: 256x256 bf16 MFMA GEMM over K = 4096 + 256 (LoRA expand folded in
// as 4 extra K-tiles read from aext/bext).
// Round-5 change vs proven round-3 skeleton: the 4 redundant leading barriers
// (reads -> BARRIER -> MFMA) are removed. Only the 4 load-bearing barriers
// remain (one per staging group + tile end). Guarantee chain: each phase's
// MFMA consumes every register of that phase's ds_reads, so by the trailing
// barrier all waves' reads of the region staged next are complete.
//   P0: read afLO+b01; MFMA lo*b01;            BAR; stage A0,A2(t+2)
//   P1: read b23;      MFMA lo*b23;            BAR; stage B0-3(t+2)
//   P2: read afHI;     MFMA hi*b01;            BAR; stage A1,A3(t+2)
//   P3:                MFMA hi*b23; vmcnt(8);  BAR
// ---------------------------------------------------------------------------
__global__ __launch_bounds__(512, 2) void gemm_lora(const short* __restrict__ xb,
                                                    const short* __restrict__ wb,
                                                    const short* __restrict__ aext,
                                                    const short* __restrict__ bext,
                                                    const float* __restrict__ base_bias,
                                                    const float* __restrict__ bias_st,
                                                    const int* __restrict__ tli,
                                                    float* __restrict__ out) {
    extern __shared__ short smem[];
    short* As0 = smem;                 // 256*64 shorts = 32 KB
    short* Bs0 = smem + 16384;
    short* As1 = smem + 32768;
    short* Bs1 = smem + 49152;

    const int tid = threadIdx.x;
    const int lane = tid & 63;
    const int wid = tid >> 6;          // 0..7
    const int wm = wid >> 2;           // 0..1
    const int wn = wid & 3;            // 0..3
    const int l15 = lane & 15;
    const int quad = lane >> 4;
    const int swz = l15 & 7;

    // bijective XCD swizzle over 256 blocks (16x16 tile grid, nwg%8==0)
    const int nid = (blockIdx.x & 7) * 32 + (blockIdx.x >> 3);
    const int t0 = (nid >> 4) * BM;
    const int o0 = (nid & 15) * BN;

    // staging source per-lane: row-within-8 = lane>>3, pre-swizzled chunk
    const int lr = lane >> 3;
    const int lc = (lane & 7) ^ lr;
    const short* agD = xb   + (size_t)(t0 + wid * 8 + lr) * D_   + lc * 8;
    const short* bgD = wb   + (size_t)(o0 + wid * 8 + lr) * D_   + lc * 8;
    const short* agE = aext + (size_t)(t0 + wid * 8 + lr) * KEXT + lc * 8;
    const short* bgE = bext + (size_t)(o0 + wid * 8 + lr) * KEXT + lc * 8;

    // region i covers tile rows [i*64, i*64+64); wave writes its 8 rows.
    // kt < 64 reads the main matrices; kt >= 64 reads the extension buffers.
    auto stA = [&](short* A_, int i, int kt) {
        const short* src = (kt < 64)
            ? agD + (size_t)i * 64 * D_   + (size_t)kt * 64
            : agE + (size_t)i * 64 * KEXT + (size_t)(kt - 64) * 64;
        load_lds16(src, A_ + (i * 64 + wid * 8) * 64);
    };
    auto stB = [&](short* B_, int i, int kt) {
        const short* src = (kt < 64)
            ? bgD + (size_t)i * 64 * D_   + (size_t)kt * 64
            : bgE + (size_t)i * 64 * KEXT + (size_t)(kt - 64) * 64;
        load_lds16(src, B_ + (i * 64 + wid * 8) * 64);
    };

    f32x4 acc[8][4];
#pragma unroll
    for (int mi = 0; mi < 8; ++mi)
#pragma unroll
        for (int ni = 0; ni < 4; ++ni) acc[mi][ni] = f32x4{0.f, 0.f, 0.f, 0.f};

    bf16x8 af[4][2];    // current qm-half A frags (reused for HI half)
    bf16x8 bfr[4][2];   // all B frags, live across the whole K-tile

    const int arow0 = wm * 128 + l15;
    const int brow0 = wn * 64 + l15;

    auto rdA = [&](const short* A_, int mi, int kk) {
        return *(const bf16x8*)&A_[(arow0 + mi * 16) * 64 + (((kk << 2) + quad) ^ swz) * 8];
    };
    auto rdB = [&](const short* B_, int ni, int kk) {
        return *(const bf16x8*)&B_[(brow0 + ni * 16) * 64 + (((kk << 2) + quad) ^ swz) * 8];
    };

    // prologue: tile 0 -> buf0, tile 1 -> buf1. Group order [A0,A2,B0..B3,A1,A3]
    stA(As0, 0, 0); stA(As0, 2, 0); stB(Bs0, 0, 0); stB(Bs0, 1, 0);
    stB(Bs0, 2, 0); stB(Bs0, 3, 0); stA(As0, 1, 0); stA(As0, 3, 0);
    stA(As1, 0, 1); stA(As1, 2, 1); stB(Bs1, 0, 1); stB(Bs1, 1, 1);
    stB(Bs1, 2, 1); stB(Bs1, 3, 1); stA(As1, 1, 1); stA(As1, 3, 1);
    asm volatile("s_waitcnt vmcnt(8)" ::: "memory");   // tile 0 landed, tile 1 in flight
    BARRIER();

    auto do_tile = [&](int t, short* A_, short* B_) {
        const bool st = (t + 2 < NT);
        const int k2 = t + 2;

        // ---- P0: read afLO + b01; MFMA lo x b01 (consumes all afLO regs)
#pragma unroll
        for (int mi = 0; mi < 4; ++mi)
#pragma unroll
            for (int kk = 0; kk < 2; ++kk) af[mi][kk] = rdA(A_, mi, kk);
#pragma unroll
        for (int ni = 0; ni < 2; ++ni)
#pragma unroll
            for (int kk = 0; kk < 2; ++kk) bfr[ni][kk] = rdB(B_, ni, kk);
        MEMF();
        __builtin_amdgcn_s_setprio(1);
#pragma unroll
        for (int kk = 0; kk < 2; ++kk)
#pragma unroll
            for (int mi = 0; mi < 4; ++mi)
#pragma unroll
                for (int ni = 0; ni < 2; ++ni)
                    acc[mi][ni] = __builtin_amdgcn_mfma_f32_16x16x32_bf16(
                        af[mi][kk], bfr[ni][kk], acc[mi][ni], 0, 0, 0);
        __builtin_amdgcn_s_setprio(0);
        BARRIER();   // all waves' afLO reads (regions 0,2) complete
        if (st) { stA(A_, 0, k2); stA(A_, 2, k2); }
        MEMF();

        // ---- P1: read b23; MFMA lo x b23 (consumes b23 regs; b01 done in P0)
#pragma unroll
        for (int ni = 2; ni < 4; ++ni)
#pragma unroll
            for (int kk = 0; kk < 2; ++kk) bfr[ni][kk] = rdB(B_, ni, kk);
        MEMF();
        __builtin_amdgcn_s_setprio(1);
#pragma unroll
        for (int kk = 0; kk < 2; ++kk)
#pragma unroll
            for (int mi = 0; mi < 4; ++mi)
#pragma unroll
                for (int ni = 2; ni < 4; ++ni)
                    acc[mi][ni] = __builtin_amdgcn_mfma_f32_16x16x32_bf16(
                        af[mi][kk], bfr[ni][kk], acc[mi][ni], 0, 0, 0);
        __builtin_amdgcn_s_setprio(0);
        BARRIER();   // all waves' B reads (region wn) complete
        if (st) { stB(B_, 0, k2); stB(B_, 1, k2); stB(B_, 2, k2); stB(B_, 3, k2); }
        MEMF();

        // ---- P2: read afHI (overwrite af regs); MFMA hi x b01
#pragma unroll
        for (int mi = 0; mi < 4; ++mi)
#pragma unroll
            for (int kk = 0; kk < 2; ++kk) af[mi][kk] = rdA(A_, mi + 4, kk);
        MEMF();
        __builtin_amdgcn_s_setprio(1);
#pragma unroll
        for (int kk = 0; kk < 2; ++kk)
#pragma unroll
            for (int mi = 0; mi < 4; ++mi)
#pragma unroll
                for (int ni = 0; ni < 2; ++ni)
                    acc[mi + 4][ni] = __builtin_amdgcn_mfma_f32_16x16x32_bf16(
                        af[mi][kk], bfr[ni][kk], acc[mi + 4][ni], 0, 0, 0);
        __builtin_amdgcn_s_setprio(0);
        BARRIER();   // all waves' afHI reads (regions 1,3) complete
        if (st) { stA(A_, 1, k2); stA(A_, 3, k2); }
        MEMF();

        // ---- P3: MFMA hi x b23; tile-end wait
        __builtin_amdgcn_s_setprio(1);
#pragma unroll
        for (int kk = 0; kk < 2; ++kk)
#pragma unroll
            for (int mi = 0; mi < 4; ++mi)
#pragma unroll
                for (int ni = 2; ni < 4; ++ni)
                    acc[mi + 4][ni] = __builtin_amdgcn_mfma_f32_16x16x32_bf16(
                        af[mi][kk], bfr[ni][kk], acc[mi + 4][ni], 0, 0, 0);
        __builtin_amdgcn_s_setprio(0);
        // youngest 8 outstanding = tile t+2's group -> tiles t+1 (and older) landed
        if (st) { asm volatile("s_waitcnt vmcnt(8)" ::: "memory"); }
        else    { asm volatile("s_waitcnt vmcnt(0)" ::: "memory"); }
        BARRIER();
    };

    for (int tt = 0; tt < NT; tt += 2) {
        do_tile(tt, As0, Bs0);
        do_tile(tt + 1, As1, Bs1);
    }

    // Epilogue: C/D layout col = lane&15, row = quad*4 + reg (verified mapping)
    const int col_base = o0 + wn * 64 + l15;
    float bb[4];
#pragma unroll
    for (int ni = 0; ni < 4; ++ni) bb[ni] = base_bias[col_base + ni * 16];
#pragma unroll
    for (int mi = 0; mi < 8; ++mi) {
#pragma unroll
        for (int reg = 0; reg < 4; ++reg) {
            const int row = t0 + wm * 128 + mi * 16 + quad * 4 + reg;
            const int idx = tli[row];
            const bool valid = (idx >= 0);
#pragma unroll
            for (int ni = 0; ni < 4; ++ni) {
                const int col = col_base + ni * 16;
                float r = acc[mi][ni][reg] + bb[ni];
                if (valid) r += bias_st[(size_t)idx * O_ + col];
                out[(size_t)row * O_ + col] = r;
            }
        }
    }
}

// ---------------------------------------------------------------------------
extern "C" void kernel_launch(void* const* d_in, const int* in_sizes, int n_in,
                              void* d_out, int out_size, void* d_ws, size_t ws_size,
                              hipStream_t stream) {
    const float* x    = (const float*)d_in[0];   // [T,D]
    const float* w    = (const float*)d_in[1];   // [O,D]
    const float* bb   = (const float*)d_in[2];   // [O]
    const float* la   = (const float*)d_in[3];   // [L,1,R,D]
    const float* lb   = (const float*)d_in[4];   // [L,1,O,R]
    const float* bs   = (const float*)d_in[5];   // [L,1,O]
    const int*   tli  = (const int*)d_in[6];     // [T]
    float* out = (float*)d_out;

    static bool inited = false;
    if (!inited) {
        (void)hipFuncSetAttribute((const void*)gemm_lora,
                                  hipFuncAttributeMaxDynamicSharedMemorySize, 131072);
        inited = true;
    }

    // workspace: xb | wb | aext | bext | abuf  (all bf16)
    unsigned short* xb   = (unsigned short*)d_ws;
    unsigned short* wb   = xb + (size_t)T_ * D_;
    unsigned short* aext = wb + (size_t)O_ * D_;
    unsigned short* bext = aext + (size_t)T_ * KEXT;
    unsigned short* abuf = bext + (size_t)O_ * KEXT;

    prep<<<35328, 256, 0, stream>>>(w, wb, x, xb, la, abuf, lb, bext, aext);
    shrink_grouped<<<512, 256, 0, stream>>>(abuf, xb, tli, aext);
    gemm_lora<<<(T_ / BM) * (O_ / BN), 512, 131072, stream>>>(
        (const short*)xb, (const short*)wb, (const short*)aext, (const short*)bext,
        bb, bs, tli, out);
}